// Round 3
// baseline (209.069 us; speedup 1.0000x reference)
//
#include <hip/hip_runtime.h>
#include <hip/hip_bf16.h>

typedef __attribute__((ext_vector_type(8))) short bf16x8;
typedef __attribute__((ext_vector_type(4))) float f32x4;
typedef __attribute__((ext_vector_type(16))) float f32x16;
typedef __attribute__((ext_vector_type(2))) unsigned int u32x2;

#define S_LEN 2048
#define DMODEL 2048
#define NHEAD 32
#define NKVH 8
#define HDIM 64
#define EQKV 3072

#if defined(__has_builtin)
#if __has_builtin(__builtin_amdgcn_global_load_lds)
#define HAVE_GLL 1
#endif
#endif

__device__ __forceinline__ unsigned short f2bf(float f) {
  unsigned int u = __float_as_uint(f);
  u = (u + 0x7FFFu + ((u >> 16) & 1u)) >> 16;
  return (unsigned short)u;
}

__device__ __forceinline__ f32x4 mfma16(bf16x8 a, bf16x8 b, f32x4 c) {
  return __builtin_amdgcn_mfma_f32_16x16x32_bf16(a, b, c, 0, 0, 0);
}
__device__ __forceinline__ f32x16 mfma32(bf16x8 a, bf16x8 b, f32x16 c) {
  return __builtin_amdgcn_mfma_f32_32x32x16_bf16(a, b, c, 0, 0, 0);
}

__device__ __forceinline__ unsigned cvtpk(float a, float b) {
  unsigned r;
  asm("v_cvt_pk_bf16_f32 %0, %1, %2" : "=v"(r) : "v"(a), "v"(b));
  return r;
}

// lane l's upper/lower-32 exchange without the LDS path (T12 primitive).
__device__ __forceinline__ void plswap(unsigned& a, unsigned& b) {
  u32x2 r = __builtin_amdgcn_permlane32_swap(a, b, false, false);
  a = r.x;
  b = r.y;
}
__device__ __forceinline__ void plswapf(float& a, float& b) {
  unsigned ua = __float_as_uint(a), ub = __float_as_uint(b);
  plswap(ua, ub);
  a = __uint_as_float(ua);
  b = __uint_as_float(ub);
}

#if HAVE_GLL
__device__ __forceinline__ void gload16(const unsigned short* g,
                                        unsigned short* l) {
  __builtin_amdgcn_global_load_lds(
      (const __attribute__((address_space(1))) unsigned int*)g,
      (__attribute__((address_space(3))) unsigned int*)l, 16, 0, 0);
}
#endif

__global__ void cast_kernel(const float* __restrict__ src,
                            unsigned short* __restrict__ dst, int n4) {
  int i = blockIdx.x * blockDim.x + threadIdx.x;
  if (i >= n4) return;
  float4 v = ((const float4*)src)[i];
  ushort4 o;
  o.x = f2bf(v.x); o.y = f2bf(v.y); o.z = f2bf(v.z); o.w = f2bf(v.w);
  ((ushort4*)dst)[i] = o;
}

// C[M][N] += A[M][K_slice] * B[N][K_slice]^T, bf16 in, f32 atomic-add out.
// 128x128 tile, 4 waves, split-K via blockIdx.z (slice = [z*KS, z*KS+KS)).
// C must be pre-zeroed. v4: split-K added because both GEMM shapes leave
// the 128^2 structure block-starved (384/256 blocks on 256 CUs ->
// Occupancy 13%, the per-k-step vmcnt(0)+barrier drain fully exposed).
// Staging via global_load_lds w=16 (m97): linear LDS dest, source chunk
// pre-swizzled (^ row&7), reads apply the same XOR.
__launch_bounds__(256)
__global__ void gemm_bt_sk(const unsigned short* __restrict__ A,
                           const unsigned short* __restrict__ B,
                           float* __restrict__ C, int M, int N, int K,
                           int KS) {
  __shared__ unsigned short As[128 * 64];
  __shared__ unsigned short Bs[128 * 64];
  const int tid = threadIdx.x;
  const int w = tid >> 6, l = tid & 63;
  const int wr = w >> 1, wc = w & 1;
  const int bm = blockIdx.y, bn = blockIdx.x;
  const int kz = blockIdx.z * KS;
  const int lr = l & 15, lq = l >> 4;

  f32x4 acc[4][4];
#pragma unroll
  for (int m = 0; m < 4; ++m)
#pragma unroll
    for (int n = 0; n < 4; ++n) acc[m][n] = (f32x4)0.f;

  // per-issue global srcs (chunk c = i*256 + tid; row=c>>3, src=(c&7)^(row&7))
  const unsigned short* gA[4];
  const unsigned short* gB[4];
#pragma unroll
  for (int i = 0; i < 4; ++i) {
    int c = i * 256 + tid;
    int row = c >> 3;
    int sc = (c & 7) ^ (row & 7);
    gA[i] = A + (size_t)(bm * 128 + row) * K + sc * 8;
    gB[i] = B + (size_t)(bn * 128 + row) * K + sc * 8;
  }

  for (int k0 = kz; k0 < kz + KS; k0 += 64) {
#if HAVE_GLL
#pragma unroll
    for (int i = 0; i < 4; ++i) {
      gload16(gA[i] + k0, &As[(i * 256 + w * 64) * 8]);
      gload16(gB[i] + k0, &Bs[(i * 256 + w * 64) * 8]);
    }
#else
#pragma unroll
    for (int i = 0; i < 4; ++i) {
      int c = i * 256 + tid;
      *(uint4*)(&As[c * 8]) = *(const uint4*)(gA[i] + k0);
      *(uint4*)(&Bs[c * 8]) = *(const uint4*)(gB[i] + k0);
    }
#endif
    __syncthreads();
#pragma unroll
    for (int ks = 0; ks < 2; ++ks) {
      bf16x8 af[4], bfr[4];
#pragma unroll
      for (int m = 0; m < 4; ++m) {
        int row = wr * 64 + m * 16 + lr;
        int ch = (ks * 4 + lq) ^ (row & 7);
        af[m] = *(const bf16x8*)(&As[row * 64 + ch * 8]);
      }
#pragma unroll
      for (int n = 0; n < 4; ++n) {
        int row = wc * 64 + n * 16 + lr;
        int ch = (ks * 4 + lq) ^ (row & 7);
        bfr[n] = *(const bf16x8*)(&Bs[row * 64 + ch * 8]);
      }
#pragma unroll
      for (int m = 0; m < 4; ++m)
#pragma unroll
        for (int n = 0; n < 4; ++n)
          acc[m][n] = mfma16(af[m], bfr[n], acc[m][n]);
    }
    __syncthreads();
  }
  const int r0 = bm * 128 + wr * 64;
  const int c0 = bn * 128 + wc * 64;
#pragma unroll
  for (int m = 0; m < 4; ++m)
#pragma unroll
    for (int n = 0; n < 4; ++n)
#pragma unroll
      for (int r = 0; r < 4; ++r)
        unsafeAtomicAdd(
            &C[(size_t)(r0 + m * 16 + 4 * lq + r) * N + c0 + n * 16 + lr],
            acc[m][n][r]);
}

// qkv f32 [S][3072] -> roped q bf16 [NH][S][64] (natural layout) and
// roped k bf16 in MFMA-FRAGMENT-TILED layout:
//   kft[kvh][kt][j][lane]*8 shorts, lane = (key&31) + 32*hi,
//   holding K[kt*32 + (key&31)][16j + 8hi + 0..7]
// so attn's kf_j load is lane-contiguous (fully coalesced 1KB/instr).
// K pre-scaled by (1/sqrt(64))*log2(e) so attn uses exp2 directly.
#define KSCALE 0.18033688011112042f
__global__ void rope_split(const float* __restrict__ qkv,
                           const float* __restrict__ cosb,
                           const float* __restrict__ sinb,
                           unsigned short* __restrict__ qb,
                           unsigned short* __restrict__ kft) {
  const int s = blockIdx.x;
  const float* row = qkv + (size_t)s * EQKV;
  for (int idx = threadIdx.x; idx < 1280; idx += 256) {
    int hh = idx >> 5;
    int m = idx & 31;
    float c = cosb[s * 32 + m];
    float sn = sinb[s * 32 + m];
    if (hh < 32) {
      float tr = row[hh * 64 + 2 * m];
      float ti = row[hh * 64 + 2 * m + 1];
      unsigned int pack = (unsigned int)f2bf(tr * c - ti * sn) |
                          ((unsigned int)f2bf(tr * sn + ti * c) << 16);
      *(unsigned int*)(qb + ((size_t)hh * S_LEN + s) * HDIM + 2 * m) = pack;
    } else {
      int kvh = hh - 32;
      float cs = c * KSCALE, ss = sn * KSCALE;
      float tr = row[2048 + kvh * 64 + 2 * m];
      float ti = row[2048 + kvh * 64 + 2 * m + 1];
      unsigned int pack = (unsigned int)f2bf(tr * cs - ti * ss) |
                          ((unsigned int)f2bf(tr * ss + ti * cs) << 16);
      // d = 2m: j = m>>3, hi = (m>>2)&1, short-offset in chunk = (m&3)*2
      int kt = s >> 5, lq = s & 31;
      int j = m >> 3, hi = (m >> 2) & 1;
      unsigned short* dst =
          kft +
          ((((size_t)kvh * 64 + kt) * 4 + j) * 64 + lq + 32 * hi) * 8 +
          (m & 3) * 2;
      *(unsigned int*)dst = pack;
    }
  }
}

// v slice of qkv -> V^T in MFMA-FRAGMENT-TILED layout:
//   vft[kvh][kt][c][lane]*8 shorts, lane = lq + 32*hi,
//   c0/c1: d = lq     (-> o0), keys kt*32 + (c&1)*16 + 8hi + 0..7
//   c2/c3: d = lq+32  (-> o1), same key mapping.
// attn's va loads become lane-contiguous (fully coalesced 1KB/instr).
__global__ void v_transpose(const float* __restrict__ qkv,
                            unsigned short* __restrict__ vft) {
  __shared__ unsigned short tile[64][72];
  const int kvh = blockIdx.x;
  const int st = blockIdx.y;  // 64-key window -> 2 kt tiles
  const int t = threadIdx.x;
  {
    const int sl = t >> 2, dg = t & 3;
    const float* src =
        qkv + (size_t)(st * 64 + sl) * EQKV + 2560 + kvh * 64 + dg * 16;
#pragma unroll
    for (int j = 0; j < 16; ++j) tile[dg * 16 + j][sl] = f2bf(src[j]);
  }
  __syncthreads();
  {
    const int kt_local = t >> 7, c = (t >> 5) & 3, lq2 = t & 31;
    const int kt = st * 2 + kt_local;
    const int d = ((c >> 1) & 1) * 32 + lq2;
    unsigned short* dbase =
        vft + (((size_t)(kvh * 64 + kt) * 4 + c) * 64) * 8;
#pragma unroll
    for (int hi2 = 0; hi2 < 2; ++hi2) {
      int koff = kt_local * 32 + (c & 1) * 16 + 8 * hi2;
      *(uint4*)(dbase + (lq2 + 32 * hi2) * 8) =
          *(const uint4*)(&tile[d][koff]);
    }
  }
}

// Flash attention, swapped-operand 32x32 + 4-way split-K per block.
// Block = (head, 32 q-rows); wave wv handles KV tiles kt = wv, wv+4, ...
// K and V^T live in fragment-tiled buffers, so all 8 per-tile loads are
// contiguous 1KB (16 lines/instr vs 64 for naive V^T / 32 for K rows).
__launch_bounds__(256, 4)
__global__ void attn_kernel(const unsigned short* __restrict__ qb,
                            const unsigned short* __restrict__ kft,
                            const unsigned short* __restrict__ vft,
                            unsigned short* __restrict__ aob) {
  __shared__ float buf[4][64][19];  // [wave][lane][o-half:16|m|l|pad]
  const int tid = threadIdx.x;
  const int wv = tid >> 6, l = tid & 63;
  const int bid = blockIdx.x;           // 2048 blocks
  const int h = bid & 31;
  const int qt = 63 - (bid >> 5);       // longest blocks first
  const int kvh = h >> 2;
  const int q0 = qt << 5;
  const int lq = l & 31;
  const int hi = l >> 5;
  const int qg = q0 + lq;

  const unsigned short* qrow = qb + ((size_t)h * S_LEN + qg) * HDIM + 8 * hi;
  bf16x8 qf[4];
#pragma unroll
  for (int j = 0; j < 4; ++j) qf[j] = *(const bf16x8*)(qrow + 16 * j);

  const unsigned short* kbase = kft + (size_t)kvh * 64 * 2048;
  const unsigned short* vbase = vft + (size_t)kvh * 64 * 2048;

  f32x16 o0 = (f32x16)0.f, o1 = (f32x16)0.f;
  float mrun = -1e30f, lrun = 0.f;
  const int ntile = qt + 1;

  for (int kt = wv; kt < ntile; kt += 4) {
    const int key0 = kt << 5;
    // --- all global loads issued up front, each fully coalesced (1KB)
    const unsigned short* kvt = kbase + (size_t)kt * 2048;
    bf16x8 kf0 = *(const bf16x8*)(kvt + l * 8);
    bf16x8 kf1 = *(const bf16x8*)(kvt + 512 + l * 8);
    bf16x8 kf2 = *(const bf16x8*)(kvt + 1024 + l * 8);
    bf16x8 kf3 = *(const bf16x8*)(kvt + 1536 + l * 8);
    const unsigned short* vvt = vbase + (size_t)kt * 2048;
    bf16x8 va00 = *(const bf16x8*)(vvt + l * 8);
    bf16x8 va01 = *(const bf16x8*)(vvt + 512 + l * 8);
    bf16x8 va10 = *(const bf16x8*)(vvt + 1024 + l * 8);
    bf16x8 va11 = *(const bf16x8*)(vvt + 1536 + l * 8);

    f32x16 s = (f32x16)0.f;
    __builtin_amdgcn_s_setprio(1);
    s = mfma32(kf0, qf[0], s);
    s = mfma32(kf1, qf[1], s);
    s = mfma32(kf2, qf[2], s);
    s = mfma32(kf3, qf[3], s);
    __builtin_amdgcn_s_setprio(0);

    float p[16];
    if (kt == ntile - 1) {  // diagonal tile: causal mask
#pragma unroll
      for (int r = 0; r < 16; ++r) {
        int key = key0 + (r & 3) + 8 * (r >> 2) + 4 * hi;
        p[r] = (key > qg) ? -1e30f : s[r];
      }
    } else {
#pragma unroll
      for (int r = 0; r < 16; ++r) p[r] = s[r];
    }
    // max tree, v_max3-fusable triples (T17)
    float a0 = fmaxf(fmaxf(p[0], p[1]), p[2]);
    float a1 = fmaxf(fmaxf(p[3], p[4]), p[5]);
    float a2 = fmaxf(fmaxf(p[6], p[7]), p[8]);
    float a3 = fmaxf(fmaxf(p[9], p[10]), p[11]);
    float a4 = fmaxf(fmaxf(p[12], p[13]), p[14]);
    float mt = fmaxf(fmaxf(fmaxf(a0, a1), a2), fmaxf(fmaxf(a3, a4), p[15]));
    float mto = mt;
    plswapf(mt, mto);
    mt = fmaxf(mt, mto);
    // T13 defer-max: only rescale when the max actually grew past THR=8
    // (log2 domain: P bounded by 2^8, safe in f32/bf16 accumulation).
    if (!__all(mt - mrun <= 8.f)) {
      float mnew = fmaxf(mrun, mt);
      float al = __builtin_amdgcn_exp2f(mrun - mnew);
      mrun = mnew;
      lrun *= al;
      o0 *= al;
      o1 *= al;
    }
#pragma unroll
    for (int r = 0; r < 16; ++r) p[r] = __builtin_amdgcn_exp2f(p[r] - mrun);
    float s0 = (p[0] + p[1]) + (p[2] + p[3]);
    float s1 = (p[4] + p[5]) + (p[6] + p[7]);
    float s2 = (p[8] + p[9]) + (p[10] + p[11]);
    float s3 = (p[12] + p[13]) + (p[14] + p[15]);
    float ts = (s0 + s1) + (s2 + s3);
    float tso = ts;
    plswapf(ts, tso);
    ts += tso;
    lrun += ts;
    // P -> bf16 B-fragments via cvt_pk + permlane32_swap (T12).
    union B8 { unsigned u[4]; bf16x8 v; } pb0, pb1;
    {
      unsigned t0 = cvtpk(p[0], p[1]), t1 = cvtpk(p[4], p[5]);
      plswap(t0, t1);
      pb0.u[0] = t0; pb0.u[2] = t1;
    }
    {
      unsigned t0 = cvtpk(p[2], p[3]), t1 = cvtpk(p[6], p[7]);
      plswap(t0, t1);
      pb0.u[1] = t0; pb0.u[3] = t1;
    }
    {
      unsigned t0 = cvtpk(p[8], p[9]), t1 = cvtpk(p[12], p[13]);
      plswap(t0, t1);
      pb1.u[0] = t0; pb1.u[2] = t1;
    }
    {
      unsigned t0 = cvtpk(p[10], p[11]), t1 = cvtpk(p[14], p[15]);
      plswap(t0, t1);
      pb1.u[1] = t0; pb1.u[3] = t1;
    }
    __builtin_amdgcn_s_setprio(1);
    o0 = mfma32(va00, pb0.v, o0);
    o0 = mfma32(va01, pb1.v, o0);
    o1 = mfma32(va10, pb0.v, o1);
    o1 = mfma32(va11, pb1.v, o1);
    __builtin_amdgcn_s_setprio(0);
  }

  // ---- two-phase split-K combine (o0 then o1, 19.4 KB LDS) ----
  // o-reg r of o{dh} maps to d = (r&3) + 8*(r>>2) + 4*hi + 32*dh;
  // wave wv combines regs [wv*4, wv*4+4) of each phase.
  {
    union F16 { f32x16 v; f32x4 q[4]; } uu;
    uu.v = o0;
    float* dst = &buf[wv][l][0];
#pragma unroll
    for (int i = 0; i < 4; ++i) *(f32x4*)(dst + 4 * i) = uu.q[i];
    dst[16] = mrun;
    dst[17] = lrun;
  }
  __syncthreads();
  float mfin = -1e30f;
#pragma unroll
  for (int w2 = 0; w2 < 4; ++w2) mfin = fmaxf(mfin, buf[w2][l][16]);
  float lsum = 0.f;
  float scl[4];
#pragma unroll
  for (int w2 = 0; w2 < 4; ++w2) {
    scl[w2] = __builtin_amdgcn_exp2f(buf[w2][l][16] - mfin);
    lsum += buf[w2][l][17] * scl[w2];
  }
  const float inv = 1.f / lsum;
  unsigned short* obase = aob + (size_t)qg * DMODEL + h * 64;
  {
    f32x4 acc = (f32x4)0.f;
#pragma unroll
    for (int w2 = 0; w2 < 4; ++w2)
      acc += *(const f32x4*)&buf[w2][l][wv * 4] * scl[w2];
    unsigned u0 = cvtpk(acc[0] * inv, acc[1] * inv);
    unsigned u1 = cvtpk(acc[2] * inv, acc[3] * inv);
    unsigned short* dsto = obase + 8 * wv + 4 * hi;
    *(unsigned*)(dsto) = u0;
    *(unsigned*)(dsto + 2) = u1;
  }
  __syncthreads();  // all phase-A reads done before overwrite
  {
    union F16 { f32x16 v; f32x4 q[4]; } uu;
    uu.v = o1;
    float* dst = &buf[wv][l][0];
#pragma unroll
    for (int i = 0; i < 4; ++i) *(f32x4*)(dst + 4 * i) = uu.q[i];
  }
  __syncthreads();
  {
    f32x4 acc = (f32x4)0.f;
#pragma unroll
    for (int w2 = 0; w2 < 4; ++w2)
      acc += *(const f32x4*)&buf[w2][l][wv * 4] * scl[w2];
    unsigned u0 = cvtpk(acc[0] * inv, acc[1] * inv);
    unsigned u1 = cvtpk(acc[2] * inv, acc[3] * inv);
    unsigned short* dsto = obase + 32 + 8 * wv + 4 * hi;
    *(unsigned*)(dsto) = u0;
    *(unsigned*)(dsto + 2) = u1;
  }
}

extern "C" void kernel_launch(void* const* d_in, const int* in_sizes, int n_in,
                              void* d_out, int out_size, void* d_ws,
                              size_t ws_size, hipStream_t stream) {
  const float* x = (const float*)d_in[0];
  const float* cosb = (const float*)d_in[1];
  const float* sinb = (const float*)d_in[2];
  const float* wqkv = (const float*)d_in[3];
  const float* wo = (const float*)d_in[4];
  float* out = (float*)d_out;
  char* ws = (char*)d_ws;
  float* qkv = (float*)(ws);                               // 25,165,824
  unsigned short* xb = (unsigned short*)(ws + 25165824);   //  8,388,608
  unsigned short* wb = (unsigned short*)(ws + 33554432);   // 12,582,912
  unsigned short* wob = (unsigned short*)(ws + 46137344);  //  8,388,608
  unsigned short* qb = (unsigned short*)(ws + 54525952);   //  8,388,608
  unsigned short* kft = (unsigned short*)(ws + 62914560);  //  2,097,152
  unsigned short* vft = (unsigned short*)(ws + 65011712);  //  2,097,152
  unsigned short* aob = (unsigned short*)(ws + 67108864);  //  8,388,608

  // split-K accumulators must start at zero (stream-ordered, capture-safe)
  hipMemsetAsync(qkv, 0, 25165824, stream);
  hipMemsetAsync(out, 0, 16777216, stream);
  cast_kernel<<<dim3(1048576 / 256), 256, 0, stream>>>(x, xb, 1048576);
  cast_kernel<<<dim3(1572864 / 256), 256, 0, stream>>>(wqkv, wb, 1572864);
  cast_kernel<<<dim3(1048576 / 256), 256, 0, stream>>>(wo, wob, 1048576);
  gemm_bt_sk<<<dim3(24, 16, 2), 256, 0, stream>>>(xb, wb, qkv, 2048, 3072,
                                                  2048, 1024);
  rope_split<<<dim3(2048), 256, 0, stream>>>(qkv, cosb, sinb, qb, kft);
  v_transpose<<<dim3(8, 32), 256, 0, stream>>>(qkv, vft);
  attn_kernel<<<dim3(2048), 256, 0, stream>>>(qb, kft, vft, aob);
  gemm_bt_sk<<<dim3(16, 16, 4), 256, 0, stream>>>(aob, wob, out, 2048, 2048,
                                                  2048, 512);
}

// Round 4
// 134.535 us; speedup vs baseline: 1.5540x; 1.5540x over previous
//
#include <hip/hip_runtime.h>
#include <hip/hip_bf16.h>

typedef __attribute__((ext_vector_type(8))) short bf16x8;
typedef __attribute__((ext_vector_type(4))) float f32x4;
typedef __attribute__((ext_vector_type(16))) float f32x16;
typedef __attribute__((ext_vector_type(2))) unsigned int u32x2;

#define S_LEN 2048
#define DMODEL 2048
#define NHEAD 32
#define NKVH 8
#define HDIM 64
#define EQKV 3072

#if defined(__has_builtin)
#if __has_builtin(__builtin_amdgcn_global_load_lds)
#define HAVE_GLL 1
#endif
#endif

__device__ __forceinline__ unsigned short f2bf(float f) {
  unsigned int u = __float_as_uint(f);
  u = (u + 0x7FFFu + ((u >> 16) & 1u)) >> 16;
  return (unsigned short)u;
}

__device__ __forceinline__ f32x4 mfma16(bf16x8 a, bf16x8 b, f32x4 c) {
  return __builtin_amdgcn_mfma_f32_16x16x32_bf16(a, b, c, 0, 0, 0);
}
__device__ __forceinline__ f32x16 mfma32(bf16x8 a, bf16x8 b, f32x16 c) {
  return __builtin_amdgcn_mfma_f32_32x32x16_bf16(a, b, c, 0, 0, 0);
}

__device__ __forceinline__ unsigned cvtpk(float a, float b) {
  unsigned r;
  asm("v_cvt_pk_bf16_f32 %0, %1, %2" : "=v"(r) : "v"(a), "v"(b));
  return r;
}

// lane l's upper/lower-32 exchange without the LDS path (T12 primitive).
__device__ __forceinline__ void plswap(unsigned& a, unsigned& b) {
  u32x2 r = __builtin_amdgcn_permlane32_swap(a, b, false, false);
  a = r.x;
  b = r.y;
}
__device__ __forceinline__ void plswapf(float& a, float& b) {
  unsigned ua = __float_as_uint(a), ub = __float_as_uint(b);
  plswap(ua, ub);
  a = __uint_as_float(ua);
  b = __uint_as_float(ub);
}

#if HAVE_GLL
__device__ __forceinline__ void gload16(const unsigned short* g,
                                        unsigned short* l) {
  __builtin_amdgcn_global_load_lds(
      (const __attribute__((address_space(1))) unsigned int*)g,
      (__attribute__((address_space(3))) unsigned int*)l, 16, 0, 0);
}
#endif

__global__ void cast_kernel(const float* __restrict__ src,
                            unsigned short* __restrict__ dst, int n4) {
  int i = blockIdx.x * blockDim.x + threadIdx.x;
  if (i >= n4) return;
  float4 v = ((const float4*)src)[i];
  ushort4 o;
  o.x = f2bf(v.x); o.y = f2bf(v.y); o.z = f2bf(v.z); o.w = f2bf(v.w);
  ((ushort4*)dst)[i] = o;
}

// C[M][N] = A[M][K] * B[N][K]^T, bf16 in, f32 out. 128x128 tile, 4 waves.
// v5: grid is 1-2 blocks/CU (384/256 blocks), so the per-k-step
// vmcnt(0)+barrier drain is fully exposed (no other block to fill it).
// Fix = T4 counted-vmcnt depth-1 pipeline: stage tile t+1 BEFORE computing
// tile t, wait vmcnt(8) (own current-tile loads only; next tile's 8 stay
// in flight across the barrier), raw s_barrier (no implicit vmcnt(0)).
// LDS 2x32KB = 64KB still lets 2 blocks/CU co-reside.
// Plus T1 XCD-chunked blockIdx swizzle (both grids %8==0 -> bijective):
// each XCD gets a contiguous band -> A-panels become L2-resident.
// Staging via global_load_lds w=16 (m97): linear LDS dest, source chunk
// pre-swizzled (^ row&7), reads apply the same XOR.
__launch_bounds__(256)
__global__ void gemm_bt(const unsigned short* __restrict__ A,
                        const unsigned short* __restrict__ B,
                        float* __restrict__ C, int M, int N, int K) {
  __shared__ unsigned short As[2][128 * 64];
  __shared__ unsigned short Bs[2][128 * 64];
  const int tid = threadIdx.x;
  const int w = tid >> 6, l = tid & 63;
  const int wr = w >> 1, wc = w & 1;
  // T1: XCD-chunked swizzle of the linear block id (nwg % 8 == 0).
  const int nwg = gridDim.x * gridDim.y;
  const int bid0 = blockIdx.y * gridDim.x + blockIdx.x;
  const int swz = (bid0 & 7) * (nwg >> 3) + (bid0 >> 3);
  const int bm = swz / gridDim.x, bn = swz % gridDim.x;
  const int lr = l & 15, lq = l >> 4;

  f32x4 acc[4][4];
#pragma unroll
  for (int m = 0; m < 4; ++m)
#pragma unroll
    for (int n = 0; n < 4; ++n) acc[m][n] = (f32x4)0.f;

  // per-issue global srcs (chunk c = i*256 + tid; row=c>>3, src=(c&7)^(row&7))
  const unsigned short* gA[4];
  const unsigned short* gB[4];
#pragma unroll
  for (int i = 0; i < 4; ++i) {
    int c = i * 256 + tid;
    int row = c >> 3;
    int sc = (c & 7) ^ (row & 7);
    gA[i] = A + (size_t)(bm * 128 + row) * K + sc * 8;
    gB[i] = B + (size_t)(bn * 128 + row) * K + sc * 8;
  }

#if HAVE_GLL
#define STAGE(bufi, k0)                                        \
  do {                                                         \
    _Pragma("unroll") for (int i = 0; i < 4; ++i) {            \
      gload16(gA[i] + (k0), &As[bufi][(i * 256 + w * 64) * 8]);\
      gload16(gB[i] + (k0), &Bs[bufi][(i * 256 + w * 64) * 8]);\
    }                                                          \
  } while (0)
#else
#define STAGE(bufi, k0)                                        \
  do {                                                         \
    _Pragma("unroll") for (int i = 0; i < 4; ++i) {            \
      int c = i * 256 + tid;                                   \
      *(uint4*)(&As[bufi][c * 8]) = *(const uint4*)(gA[i] + (k0)); \
      *(uint4*)(&Bs[bufi][c * 8]) = *(const uint4*)(gB[i] + (k0)); \
    }                                                          \
  } while (0)
#endif

#define COMPUTE(bufi)                                                     \
  do {                                                                    \
    _Pragma("unroll") for (int ks = 0; ks < 2; ++ks) {                    \
      bf16x8 af[4], bfr[4];                                               \
      _Pragma("unroll") for (int m = 0; m < 4; ++m) {                     \
        int row = wr * 64 + m * 16 + lr;                                  \
        int ch = (ks * 4 + lq) ^ (row & 7);                               \
        af[m] = *(const bf16x8*)(&As[bufi][row * 64 + ch * 8]);           \
      }                                                                   \
      _Pragma("unroll") for (int n = 0; n < 4; ++n) {                     \
        int row = wc * 64 + n * 16 + lr;                                  \
        int ch = (ks * 4 + lq) ^ (row & 7);                               \
        bfr[n] = *(const bf16x8*)(&Bs[bufi][row * 64 + ch * 8]);          \
      }                                                                   \
      _Pragma("unroll") for (int m = 0; m < 4; ++m)                       \
          _Pragma("unroll") for (int n = 0; n < 4; ++n)                   \
              acc[m][n] = mfma16(af[m], bfr[n], acc[m][n]);               \
    }                                                                     \
  } while (0)

  const int nt = K >> 6;  // k-steps of 64
  // prologue: stage tile 0
  STAGE(0, 0);
  int cur = 0;
#if HAVE_GLL
  for (int t = 0; t < nt - 1; ++t) {
    STAGE(cur ^ 1, (t + 1) * 64);  // next tile's 8 loads issued first
    // wait for OWN current-tile loads (8 newest stay outstanding)
    asm volatile("s_waitcnt vmcnt(8)" ::: "memory");
    __builtin_amdgcn_sched_barrier(0);
    __builtin_amdgcn_s_barrier();  // all waves' tile-t loads landed
    COMPUTE(cur);
    // all my LDS reads complete before anyone overwrites this buffer
    asm volatile("s_waitcnt lgkmcnt(0)" ::: "memory");
    __builtin_amdgcn_sched_barrier(0);
    __builtin_amdgcn_s_barrier();
    cur ^= 1;
  }
  asm volatile("s_waitcnt vmcnt(0)" ::: "memory");
  __builtin_amdgcn_sched_barrier(0);
  __builtin_amdgcn_s_barrier();
  COMPUTE(cur);
#else
  for (int t = 0; t < nt; ++t) {
    if (t > 0) STAGE(cur, t * 64);
    __syncthreads();
    COMPUTE(cur);
    __syncthreads();
  }
#endif
#undef STAGE
#undef COMPUTE

  const int r0 = bm * 128 + wr * 64;
  const int c0 = bn * 128 + wc * 64;
#pragma unroll
  for (int m = 0; m < 4; ++m)
#pragma unroll
    for (int n = 0; n < 4; ++n)
#pragma unroll
      for (int r = 0; r < 4; ++r)
        C[(size_t)(r0 + m * 16 + 4 * lq + r) * N + c0 + n * 16 + lr] =
            acc[m][n][r];
}

// qkv f32 [S][3072] -> roped q bf16 [NH][S][64] (natural layout) and
// roped k bf16 in MFMA-FRAGMENT-TILED layout:
//   kft[kvh][kt][j][lane]*8 shorts, lane = (key&31) + 32*hi,
//   holding K[kt*32 + (key&31)][16j + 8hi + 0..7]
// so attn's kf_j load is lane-contiguous (fully coalesced 1KB/instr).
// K pre-scaled by (1/sqrt(64))*log2(e) so attn uses exp2 directly.
#define KSCALE 0.18033688011112042f
__global__ void rope_split(const float* __restrict__ qkv,
                           const float* __restrict__ cosb,
                           const float* __restrict__ sinb,
                           unsigned short* __restrict__ qb,
                           unsigned short* __restrict__ kft) {
  const int s = blockIdx.x;
  const float* row = qkv + (size_t)s * EQKV;
  for (int idx = threadIdx.x; idx < 1280; idx += 256) {
    int hh = idx >> 5;
    int m = idx & 31;
    float c = cosb[s * 32 + m];
    float sn = sinb[s * 32 + m];
    if (hh < 32) {
      float tr = row[hh * 64 + 2 * m];
      float ti = row[hh * 64 + 2 * m + 1];
      unsigned int pack = (unsigned int)f2bf(tr * c - ti * sn) |
                          ((unsigned int)f2bf(tr * sn + ti * c) << 16);
      *(unsigned int*)(qb + ((size_t)hh * S_LEN + s) * HDIM + 2 * m) = pack;
    } else {
      int kvh = hh - 32;
      float cs = c * KSCALE, ss = sn * KSCALE;
      float tr = row[2048 + kvh * 64 + 2 * m];
      float ti = row[2048 + kvh * 64 + 2 * m + 1];
      unsigned int pack = (unsigned int)f2bf(tr * cs - ti * ss) |
                          ((unsigned int)f2bf(tr * ss + ti * cs) << 16);
      // d = 2m: j = m>>3, hi = (m>>2)&1, short-offset in chunk = (m&3)*2
      int kt = s >> 5, lq = s & 31;
      int j = m >> 3, hi = (m >> 2) & 1;
      unsigned short* dst =
          kft +
          ((((size_t)kvh * 64 + kt) * 4 + j) * 64 + lq + 32 * hi) * 8 +
          (m & 3) * 2;
      *(unsigned int*)dst = pack;
    }
  }
}

// v slice of qkv -> V^T in MFMA-FRAGMENT-TILED layout:
//   vft[kvh][kt][c][lane]*8 shorts, lane = lq + 32*hi,
//   c0/c1: d = lq     (-> o0), keys kt*32 + (c&1)*16 + 8hi + 0..7
//   c2/c3: d = lq+32  (-> o1), same key mapping.
// attn's va loads become lane-contiguous (fully coalesced 1KB/instr).
__global__ void v_transpose(const float* __restrict__ qkv,
                            unsigned short* __restrict__ vft) {
  __shared__ unsigned short tile[64][72];
  const int kvh = blockIdx.x;
  const int st = blockIdx.y;  // 64-key window -> 2 kt tiles
  const int t = threadIdx.x;
  {
    const int sl = t >> 2, dg = t & 3;
    const float* src =
        qkv + (size_t)(st * 64 + sl) * EQKV + 2560 + kvh * 64 + dg * 16;
#pragma unroll
    for (int j = 0; j < 16; ++j) tile[dg * 16 + j][sl] = f2bf(src[j]);
  }
  __syncthreads();
  {
    const int kt_local = t >> 7, c = (t >> 5) & 3, lq2 = t & 31;
    const int kt = st * 2 + kt_local;
    const int d = ((c >> 1) & 1) * 32 + lq2;
    unsigned short* dbase =
        vft + (((size_t)(kvh * 64 + kt) * 4 + c) * 64) * 8;
#pragma unroll
    for (int hi2 = 0; hi2 < 2; ++hi2) {
      int koff = kt_local * 32 + (c & 1) * 16 + 8 * hi2;
      *(uint4*)(dbase + (lq2 + 32 * hi2) * 8) =
          *(const uint4*)(&tile[d][koff]);
    }
  }
}

// Flash attention, swapped-operand 32x32 + 4-way split-K per block.
// Block = (head, 32 q-rows); wave wv handles KV tiles kt = wv, wv+4, ...
// K and V^T live in fragment-tiled buffers, so all 8 per-tile loads are
// contiguous 1KB (16 lines/instr vs 64 for naive V^T / 32 for K rows).
__launch_bounds__(256, 4)
__global__ void attn_kernel(const unsigned short* __restrict__ qb,
                            const unsigned short* __restrict__ kft,
                            const unsigned short* __restrict__ vft,
                            unsigned short* __restrict__ aob) {
  __shared__ float buf[4][64][19];  // [wave][lane][o-half:16|m|l|pad]
  const int tid = threadIdx.x;
  const int wv = tid >> 6, l = tid & 63;
  const int bid = blockIdx.x;           // 2048 blocks
  const int h = bid & 31;
  const int qt = 63 - (bid >> 5);       // longest blocks first
  const int kvh = h >> 2;
  const int q0 = qt << 5;
  const int lq = l & 31;
  const int hi = l >> 5;
  const int qg = q0 + lq;

  const unsigned short* qrow = qb + ((size_t)h * S_LEN + qg) * HDIM + 8 * hi;
  bf16x8 qf[4];
#pragma unroll
  for (int j = 0; j < 4; ++j) qf[j] = *(const bf16x8*)(qrow + 16 * j);

  const unsigned short* kbase = kft + (size_t)kvh * 64 * 2048;
  const unsigned short* vbase = vft + (size_t)kvh * 64 * 2048;

  f32x16 o0 = (f32x16)0.f, o1 = (f32x16)0.f;
  float mrun = -1e30f, lrun = 0.f;
  const int ntile = qt + 1;

  for (int kt = wv; kt < ntile; kt += 4) {
    const int key0 = kt << 5;
    // --- all global loads issued up front, each fully coalesced (1KB)
    const unsigned short* kvt = kbase + (size_t)kt * 2048;
    bf16x8 kf0 = *(const bf16x8*)(kvt + l * 8);
    bf16x8 kf1 = *(const bf16x8*)(kvt + 512 + l * 8);
    bf16x8 kf2 = *(const bf16x8*)(kvt + 1024 + l * 8);
    bf16x8 kf3 = *(const bf16x8*)(kvt + 1536 + l * 8);
    const unsigned short* vvt = vbase + (size_t)kt * 2048;
    bf16x8 va00 = *(const bf16x8*)(vvt + l * 8);
    bf16x8 va01 = *(const bf16x8*)(vvt + 512 + l * 8);
    bf16x8 va10 = *(const bf16x8*)(vvt + 1024 + l * 8);
    bf16x8 va11 = *(const bf16x8*)(vvt + 1536 + l * 8);

    f32x16 s = (f32x16)0.f;
    __builtin_amdgcn_s_setprio(1);
    s = mfma32(kf0, qf[0], s);
    s = mfma32(kf1, qf[1], s);
    s = mfma32(kf2, qf[2], s);
    s = mfma32(kf3, qf[3], s);
    __builtin_amdgcn_s_setprio(0);

    float p[16];
    if (kt == ntile - 1) {  // diagonal tile: causal mask
#pragma unroll
      for (int r = 0; r < 16; ++r) {
        int key = key0 + (r & 3) + 8 * (r >> 2) + 4 * hi;
        p[r] = (key > qg) ? -1e30f : s[r];
      }
    } else {
#pragma unroll
      for (int r = 0; r < 16; ++r) p[r] = s[r];
    }
    // max tree, v_max3-fusable triples (T17)
    float a0 = fmaxf(fmaxf(p[0], p[1]), p[2]);
    float a1 = fmaxf(fmaxf(p[3], p[4]), p[5]);
    float a2 = fmaxf(fmaxf(p[6], p[7]), p[8]);
    float a3 = fmaxf(fmaxf(p[9], p[10]), p[11]);
    float a4 = fmaxf(fmaxf(p[12], p[13]), p[14]);
    float mt = fmaxf(fmaxf(fmaxf(a0, a1), a2), fmaxf(fmaxf(a3, a4), p[15]));
    float mto = mt;
    plswapf(mt, mto);
    mt = fmaxf(mt, mto);
    // T13 defer-max: only rescale when the max actually grew past THR=8
    // (log2 domain: P bounded by 2^8, safe in f32/bf16 accumulation).
    if (!__all(mt - mrun <= 8.f)) {
      float mnew = fmaxf(mrun, mt);
      float al = __builtin_amdgcn_exp2f(mrun - mnew);
      mrun = mnew;
      lrun *= al;
      o0 *= al;
      o1 *= al;
    }
#pragma unroll
    for (int r = 0; r < 16; ++r) p[r] = __builtin_amdgcn_exp2f(p[r] - mrun);
    float s0 = (p[0] + p[1]) + (p[2] + p[3]);
    float s1 = (p[4] + p[5]) + (p[6] + p[7]);
    float s2 = (p[8] + p[9]) + (p[10] + p[11]);
    float s3 = (p[12] + p[13]) + (p[14] + p[15]);
    float ts = (s0 + s1) + (s2 + s3);
    float tso = ts;
    plswapf(ts, tso);
    ts += tso;
    lrun += ts;
    // P -> bf16 B-fragments via cvt_pk + permlane32_swap (T12).
    union B8 { unsigned u[4]; bf16x8 v; } pb0, pb1;
    {
      unsigned t0 = cvtpk(p[0], p[1]), t1 = cvtpk(p[4], p[5]);
      plswap(t0, t1);
      pb0.u[0] = t0; pb0.u[2] = t1;
    }
    {
      unsigned t0 = cvtpk(p[2], p[3]), t1 = cvtpk(p[6], p[7]);
      plswap(t0, t1);
      pb0.u[1] = t0; pb0.u[3] = t1;
    }
    {
      unsigned t0 = cvtpk(p[8], p[9]), t1 = cvtpk(p[12], p[13]);
      plswap(t0, t1);
      pb1.u[0] = t0; pb1.u[2] = t1;
    }
    {
      unsigned t0 = cvtpk(p[10], p[11]), t1 = cvtpk(p[14], p[15]);
      plswap(t0, t1);
      pb1.u[1] = t0; pb1.u[3] = t1;
    }
    __builtin_amdgcn_s_setprio(1);
    o0 = mfma32(va00, pb0.v, o0);
    o0 = mfma32(va01, pb1.v, o0);
    o1 = mfma32(va10, pb0.v, o1);
    o1 = mfma32(va11, pb1.v, o1);
    __builtin_amdgcn_s_setprio(0);
  }

  // ---- two-phase split-K combine (o0 then o1, 19.4 KB LDS) ----
  // o-reg r of o{dh} maps to d = (r&3) + 8*(r>>2) + 4*hi + 32*dh;
  // wave wv combines regs [wv*4, wv*4+4) of each phase.
  {
    union F16 { f32x16 v; f32x4 q[4]; } uu;
    uu.v = o0;
    float* dst = &buf[wv][l][0];
#pragma unroll
    for (int i = 0; i < 4; ++i) *(f32x4*)(dst + 4 * i) = uu.q[i];
    dst[16] = mrun;
    dst[17] = lrun;
  }
  __syncthreads();
  float mfin = -1e30f;
#pragma unroll
  for (int w2 = 0; w2 < 4; ++w2) mfin = fmaxf(mfin, buf[w2][l][16]);
  float lsum = 0.f;
  float scl[4];
#pragma unroll
  for (int w2 = 0; w2 < 4; ++w2) {
    scl[w2] = __builtin_amdgcn_exp2f(buf[w2][l][16] - mfin);
    lsum += buf[w2][l][17] * scl[w2];
  }
  const float inv = 1.f / lsum;
  unsigned short* obase = aob + (size_t)qg * DMODEL + h * 64;
  {
    f32x4 acc = (f32x4)0.f;
#pragma unroll
    for (int w2 = 0; w2 < 4; ++w2)
      acc += *(const f32x4*)&buf[w2][l][wv * 4] * scl[w2];
    unsigned u0 = cvtpk(acc[0] * inv, acc[1] * inv);
    unsigned u1 = cvtpk(acc[2] * inv, acc[3] * inv);
    unsigned short* dsto = obase + 8 * wv + 4 * hi;
    *(unsigned*)(dsto) = u0;
    *(unsigned*)(dsto + 2) = u1;
  }
  __syncthreads();  // all phase-A reads done before overwrite
  {
    union F16 { f32x16 v; f32x4 q[4]; } uu;
    uu.v = o1;
    float* dst = &buf[wv][l][0];
#pragma unroll
    for (int i = 0; i < 4; ++i) *(f32x4*)(dst + 4 * i) = uu.q[i];
  }
  __syncthreads();
  {
    f32x4 acc = (f32x4)0.f;
#pragma unroll
    for (int w2 = 0; w2 < 4; ++w2)
      acc += *(const f32x4*)&buf[w2][l][wv * 4] * scl[w2];
    unsigned u0 = cvtpk(acc[0] * inv, acc[1] * inv);
    unsigned u1 = cvtpk(acc[2] * inv, acc[3] * inv);
    unsigned short* dsto = obase + 32 + 8 * wv + 4 * hi;
    *(unsigned*)(dsto) = u0;
    *(unsigned*)(dsto + 2) = u1;
  }
}

extern "C" void kernel_launch(void* const* d_in, const int* in_sizes, int n_in,
                              void* d_out, int out_size, void* d_ws,
                              size_t ws_size, hipStream_t stream) {
  const float* x = (const float*)d_in[0];
  const float* cosb = (const float*)d_in[1];
  const float* sinb = (const float*)d_in[2];
  const float* wqkv = (const float*)d_in[3];
  const float* wo = (const float*)d_in[4];
  float* out = (float*)d_out;
  char* ws = (char*)d_ws;
  float* qkv = (float*)(ws);                               // 25,165,824
  unsigned short* xb = (unsigned short*)(ws + 25165824);   //  8,388,608
  unsigned short* wb = (unsigned short*)(ws + 33554432);   // 12,582,912
  unsigned short* wob = (unsigned short*)(ws + 46137344);  //  8,388,608
  unsigned short* qb = (unsigned short*)(ws + 54525952);   //  8,388,608
  unsigned short* kft = (unsigned short*)(ws + 62914560);  //  2,097,152
  unsigned short* vft = (unsigned short*)(ws + 65011712);  //  2,097,152
  unsigned short* aob = (unsigned short*)(ws + 67108864);  //  8,388,608

  cast_kernel<<<dim3(1048576 / 256), 256, 0, stream>>>(x, xb, 1048576);
  cast_kernel<<<dim3(1572864 / 256), 256, 0, stream>>>(wqkv, wb, 1572864);
  cast_kernel<<<dim3(1048576 / 256), 256, 0, stream>>>(wo, wob, 1048576);
  gemm_bt<<<dim3(24, 16), 256, 0, stream>>>(xb, wb, qkv, 2048, 3072, 2048);
  rope_split<<<dim3(2048), 256, 0, stream>>>(qkv, cosb, sinb, qb, kft);
  v_transpose<<<dim3(8, 32), 256, 0, stream>>>(qkv, vft);
  attn_kernel<<<dim3(2048), 256, 0, stream>>>(qb, kft, vft, aob);
  gemm_bt<<<dim3(16, 16), 256, 0, stream>>>(aob, wob, out, 2048, 2048, 2048);
}

// Round 5
// 121.591 us; speedup vs baseline: 1.7194x; 1.1065x over previous
//
#include <hip/hip_runtime.h>
#include <hip/hip_bf16.h>

typedef __attribute__((ext_vector_type(8))) short bf16x8;
typedef __attribute__((ext_vector_type(4))) float f32x4;
typedef __attribute__((ext_vector_type(16))) float f32x16;
typedef __attribute__((ext_vector_type(2))) unsigned int u32x2;

#define S_LEN 2048
#define DMODEL 2048
#define NHEAD 32
#define NKVH 8
#define HDIM 64
#define EQKV 3072

#if defined(__has_builtin)
#if __has_builtin(__builtin_amdgcn_global_load_lds)
#define HAVE_GLL 1
#endif
#endif

__device__ __forceinline__ unsigned short f2bf(float f) {
  unsigned int u = __float_as_uint(f);
  u = (u + 0x7FFFu + ((u >> 16) & 1u)) >> 16;
  return (unsigned short)u;
}

__device__ __forceinline__ f32x4 mfma16(bf16x8 a, bf16x8 b, f32x4 c) {
  return __builtin_amdgcn_mfma_f32_16x16x32_bf16(a, b, c, 0, 0, 0);
}
__device__ __forceinline__ f32x16 mfma32(bf16x8 a, bf16x8 b, f32x16 c) {
  return __builtin_amdgcn_mfma_f32_32x32x16_bf16(a, b, c, 0, 0, 0);
}

__device__ __forceinline__ unsigned cvtpk(float a, float b) {
  unsigned r;
  asm("v_cvt_pk_bf16_f32 %0, %1, %2" : "=v"(r) : "v"(a), "v"(b));
  return r;
}

// lane l's upper/lower-32 exchange without the LDS path (T12 primitive).
__device__ __forceinline__ void plswap(unsigned& a, unsigned& b) {
  u32x2 r = __builtin_amdgcn_permlane32_swap(a, b, false, false);
  a = r.x;
  b = r.y;
}
__device__ __forceinline__ void plswapf(float& a, float& b) {
  unsigned ua = __float_as_uint(a), ub = __float_as_uint(b);
  plswap(ua, ub);
  a = __uint_as_float(ua);
  b = __uint_as_float(ub);
}

#if HAVE_GLL
__device__ __forceinline__ void gload16(const unsigned short* g,
                                        unsigned short* l) {
  __builtin_amdgcn_global_load_lds(
      (const __attribute__((address_space(1))) unsigned int*)g,
      (__attribute__((address_space(3))) unsigned int*)l, 16, 0, 0);
}
#endif

// One launch casts all three f32 buffers to bf16 (x, wqkv, wo).
__global__ void cast3_kernel(const float* __restrict__ x,
                             const float* __restrict__ wqkv,
                             const float* __restrict__ wo,
                             unsigned short* __restrict__ xb,
                             unsigned short* __restrict__ wb,
                             unsigned short* __restrict__ wob) {
  int i = blockIdx.x * blockDim.x + threadIdx.x;
  const float* s;
  unsigned short* d;
  int j;
  if (i < 1048576) {
    s = x; d = xb; j = i;
  } else if (i < 2621440) {
    s = wqkv; d = wb; j = i - 1048576;
  } else {
    s = wo; d = wob; j = i - 2621440;
  }
  float4 v = ((const float4*)s)[j];
  ushort4 o;
  o.x = f2bf(v.x); o.y = f2bf(v.y); o.z = f2bf(v.z); o.w = f2bf(v.w);
  ((ushort4*)d)[j] = o;
}

// C[M][N] = A[M][K] * B[N][K]^T, bf16 in, f32 out. 128x64 tile, 4 waves.
// v6: tile narrowed 128x128 -> 128x64. Both GEMM shapes were block-starved
// (384/256 blocks = 1-1.5/CU, Occupancy 12.7%): per-step compute (~350cy)
// can't cover HBM-class miss latency (~900cy) even depth-1-pipelined.
// 128x64 gives 768/512 blocks with 48KB LDS -> 3 (resp 2) co-resident
// blocks/CU; cross-block overlap fills the stall (m114 mechanism).
// Keeps: T4 counted-vmcnt (now 6 loads/stage) depth-1 pipeline, raw
// s_barrier, T1 XCD-chunked swizzle, m97 global_load_lds w=16 staging
// with pre-swizzled source chunks (^ row&7).
__launch_bounds__(256)
__global__ void gemm_bt(const unsigned short* __restrict__ A,
                        const unsigned short* __restrict__ B,
                        float* __restrict__ C, int M, int N, int K) {
  __shared__ unsigned short As[2][128 * 64];
  __shared__ unsigned short Bs[2][64 * 64];
  const int tid = threadIdx.x;
  const int w = tid >> 6, l = tid & 63;
  const int wr = w >> 1, wc = w & 1;
  // T1: XCD-chunked swizzle of the linear block id (nwg % 8 == 0).
  const int nwg = gridDim.x * gridDim.y;
  const int bid0 = blockIdx.y * gridDim.x + blockIdx.x;
  const int swz = (bid0 & 7) * (nwg >> 3) + (bid0 >> 3);
  const int bm = swz / gridDim.x, bn = swz % gridDim.x;
  const int lr = l & 15, lq = l >> 4;

  f32x4 acc[4][2];
#pragma unroll
  for (int m = 0; m < 4; ++m)
#pragma unroll
    for (int n = 0; n < 2; ++n) acc[m][n] = (f32x4)0.f;

  // per-issue global srcs (chunk c = i*256 + tid; row=c>>3, src=(c&7)^(row&7))
  const unsigned short* gA[4];
  const unsigned short* gB[2];
#pragma unroll
  for (int i = 0; i < 4; ++i) {
    int c = i * 256 + tid;
    int row = c >> 3;
    int sc = (c & 7) ^ (row & 7);
    gA[i] = A + (size_t)(bm * 128 + row) * K + sc * 8;
  }
#pragma unroll
  for (int i = 0; i < 2; ++i) {
    int c = i * 256 + tid;
    int row = c >> 3;
    int sc = (c & 7) ^ (row & 7);
    gB[i] = B + (size_t)(bn * 64 + row) * K + sc * 8;
  }

#if HAVE_GLL
#define STAGE(bufi, k0)                                            \
  do {                                                             \
    _Pragma("unroll") for (int i = 0; i < 4; ++i)                  \
        gload16(gA[i] + (k0), &As[bufi][(i * 256 + w * 64) * 8]);  \
    _Pragma("unroll") for (int i = 0; i < 2; ++i)                  \
        gload16(gB[i] + (k0), &Bs[bufi][(i * 256 + w * 64) * 8]);  \
  } while (0)
#else
#define STAGE(bufi, k0)                                            \
  do {                                                             \
    _Pragma("unroll") for (int i = 0; i < 4; ++i) {                \
      int c = i * 256 + tid;                                       \
      *(uint4*)(&As[bufi][c * 8]) = *(const uint4*)(gA[i] + (k0)); \
    }                                                              \
    _Pragma("unroll") for (int i = 0; i < 2; ++i) {                \
      int c = i * 256 + tid;                                       \
      *(uint4*)(&Bs[bufi][c * 8]) = *(const uint4*)(gB[i] + (k0)); \
    }                                                              \
  } while (0)
#endif

#define COMPUTE(bufi)                                                     \
  do {                                                                    \
    _Pragma("unroll") for (int ks = 0; ks < 2; ++ks) {                    \
      bf16x8 af[4], bfr[2];                                               \
      _Pragma("unroll") for (int m = 0; m < 4; ++m) {                     \
        int row = wr * 64 + m * 16 + lr;                                  \
        int ch = (ks * 4 + lq) ^ (row & 7);                               \
        af[m] = *(const bf16x8*)(&As[bufi][row * 64 + ch * 8]);           \
      }                                                                   \
      _Pragma("unroll") for (int n = 0; n < 2; ++n) {                     \
        int row = wc * 32 + n * 16 + lr;                                  \
        int ch = (ks * 4 + lq) ^ (row & 7);                               \
        bfr[n] = *(const bf16x8*)(&Bs[bufi][row * 64 + ch * 8]);          \
      }                                                                   \
      _Pragma("unroll") for (int m = 0; m < 4; ++m)                       \
          _Pragma("unroll") for (int n = 0; n < 2; ++n)                   \
              acc[m][n] = mfma16(af[m], bfr[n], acc[m][n]);               \
    }                                                                     \
  } while (0)

  const int nt = K >> 6;  // k-steps of 64
  STAGE(0, 0);
  int cur = 0;
#if HAVE_GLL
  for (int t = 0; t < nt - 1; ++t) {
    STAGE(cur ^ 1, (t + 1) * 64);  // next tile's 6 loads issued first
    // wait for OWN current-tile loads (6 newest stay outstanding)
    asm volatile("s_waitcnt vmcnt(6)" ::: "memory");
    __builtin_amdgcn_sched_barrier(0);
    __builtin_amdgcn_s_barrier();  // all waves' tile-t loads landed
    COMPUTE(cur);
    // all my LDS reads complete before anyone overwrites this buffer
    asm volatile("s_waitcnt lgkmcnt(0)" ::: "memory");
    __builtin_amdgcn_sched_barrier(0);
    __builtin_amdgcn_s_barrier();
    cur ^= 1;
  }
  asm volatile("s_waitcnt vmcnt(0)" ::: "memory");
  __builtin_amdgcn_sched_barrier(0);
  __builtin_amdgcn_s_barrier();
  COMPUTE(cur);
#else
  for (int t = 0; t < nt; ++t) {
    if (t > 0) STAGE(cur, t * 64);
    __syncthreads();
    COMPUTE(cur);
    __syncthreads();
  }
#endif
#undef STAGE
#undef COMPUTE

  const int r0 = bm * 128 + wr * 64;
  const int c0 = bn * 64 + wc * 32;
#pragma unroll
  for (int m = 0; m < 4; ++m)
#pragma unroll
    for (int n = 0; n < 2; ++n)
#pragma unroll
      for (int r = 0; r < 4; ++r)
        C[(size_t)(r0 + m * 16 + 4 * lq + r) * N + c0 + n * 16 + lr] =
            acc[m][n][r];
}

// qkv f32 [S][3072] -> roped q bf16 [NH][S][64] (natural layout) and
// roped k bf16 in MFMA-FRAGMENT-TILED layout:
//   kft[kvh][kt][j][lane]*8 shorts, lane = (key&31) + 32*hi,
//   holding K[kt*32 + (key&31)][16j + 8hi + 0..7]
// so attn's kf_j load is lane-contiguous (fully coalesced 1KB/instr).
// K pre-scaled by (1/sqrt(64))*log2(e) so attn uses exp2 directly.
#define KSCALE 0.18033688011112042f
__global__ void rope_split(const float* __restrict__ qkv,
                           const float* __restrict__ cosb,
                           const float* __restrict__ sinb,
                           unsigned short* __restrict__ qb,
                           unsigned short* __restrict__ kft) {
  const int s = blockIdx.x;
  const float* row = qkv + (size_t)s * EQKV;
  for (int idx = threadIdx.x; idx < 1280; idx += 256) {
    int hh = idx >> 5;
    int m = idx & 31;
    float c = cosb[s * 32 + m];
    float sn = sinb[s * 32 + m];
    if (hh < 32) {
      float tr = row[hh * 64 + 2 * m];
      float ti = row[hh * 64 + 2 * m + 1];
      unsigned int pack = (unsigned int)f2bf(tr * c - ti * sn) |
                          ((unsigned int)f2bf(tr * sn + ti * c) << 16);
      *(unsigned int*)(qb + ((size_t)hh * S_LEN + s) * HDIM + 2 * m) = pack;
    } else {
      int kvh = hh - 32;
      float cs = c * KSCALE, ss = sn * KSCALE;
      float tr = row[2048 + kvh * 64 + 2 * m];
      float ti = row[2048 + kvh * 64 + 2 * m + 1];
      unsigned int pack = (unsigned int)f2bf(tr * cs - ti * ss) |
                          ((unsigned int)f2bf(tr * ss + ti * cs) << 16);
      // d = 2m: j = m>>3, hi = (m>>2)&1, short-offset in chunk = (m&3)*2
      int kt = s >> 5, lq = s & 31;
      int j = m >> 3, hi = (m >> 2) & 1;
      unsigned short* dst =
          kft +
          ((((size_t)kvh * 64 + kt) * 4 + j) * 64 + lq + 32 * hi) * 8 +
          (m & 3) * 2;
      *(unsigned int*)dst = pack;
    }
  }
}

// v slice of qkv -> V^T in MFMA-FRAGMENT-TILED layout:
//   vft[kvh][kt][c][lane]*8 shorts, lane = lq + 32*hi,
//   c0/c1: d = lq     (-> o0), keys kt*32 + (c&1)*16 + 8hi + 0..7
//   c2/c3: d = lq+32  (-> o1), same key mapping.
// attn's va loads become lane-contiguous (fully coalesced 1KB/instr).
__global__ void v_transpose(const float* __restrict__ qkv,
                            unsigned short* __restrict__ vft) {
  __shared__ unsigned short tile[64][72];
  const int kvh = blockIdx.x;
  const int st = blockIdx.y;  // 64-key window -> 2 kt tiles
  const int t = threadIdx.x;
  {
    const int sl = t >> 2, dg = t & 3;
    const float* src =
        qkv + (size_t)(st * 64 + sl) * EQKV + 2560 + kvh * 64 + dg * 16;
#pragma unroll
    for (int j = 0; j < 16; ++j) tile[dg * 16 + j][sl] = f2bf(src[j]);
  }
  __syncthreads();
  {
    const int kt_local = t >> 7, c = (t >> 5) & 3, lq2 = t & 31;
    const int kt = st * 2 + kt_local;
    const int d = ((c >> 1) & 1) * 32 + lq2;
    unsigned short* dbase =
        vft + (((size_t)(kvh * 64 + kt) * 4 + c) * 64) * 8;
#pragma unroll
    for (int hi2 = 0; hi2 < 2; ++hi2) {
      int koff = kt_local * 32 + (c & 1) * 16 + 8 * hi2;
      *(uint4*)(dbase + (lq2 + 32 * hi2) * 8) =
          *(const uint4*)(&tile[d][koff]);
    }
  }
}

// Flash attention, swapped-operand 32x32 + 4-way split-K per block.
// Block = (head, 32 q-rows); wave wv handles KV tiles kt = wv, wv+4, ...
// v6: inner loop unrolled 2x (pair kt, kt+4): 16 coalesced loads in
// flight (vs 8) and ONE merged online-softmax per 64 keys (one max tree,
// one rescale test, one lrun update) -> halves inter-MFMA VALU.
// Tile-a of a pair is never diagonal (kt <= ntile-5); causal mask only
// on tile-b / tail. launch_bounds(256,3): ~170 VGPR cap, 3 blocks/CU.
__launch_bounds__(256, 3)
__global__ void attn_kernel(const unsigned short* __restrict__ qb,
                            const unsigned short* __restrict__ kft,
                            const unsigned short* __restrict__ vft,
                            unsigned short* __restrict__ aob) {
  __shared__ float buf[4][64][19];  // [wave][lane][o-half:16|m|l|pad]
  const int tid = threadIdx.x;
  const int wv = tid >> 6, l = tid & 63;
  const int bid = blockIdx.x;           // 2048 blocks
  const int h = bid & 31;
  const int qt = 63 - (bid >> 5);       // longest blocks first
  const int kvh = h >> 2;
  const int q0 = qt << 5;
  const int lq = l & 31;
  const int hi = l >> 5;
  const int qg = q0 + lq;

  const unsigned short* qrow = qb + ((size_t)h * S_LEN + qg) * HDIM + 8 * hi;
  bf16x8 qf[4];
#pragma unroll
  for (int j = 0; j < 4; ++j) qf[j] = *(const bf16x8*)(qrow + 16 * j);

  const unsigned short* kbase = kft + (size_t)kvh * 64 * 2048;
  const unsigned short* vbase = vft + (size_t)kvh * 64 * 2048;

  f32x16 o0 = (f32x16)0.f, o1 = (f32x16)0.f;
  float mrun = -1e30f, lrun = 0.f;
  const int ntile = qt + 1;

  int kt = wv;
  // ---- paired tiles: a = kt (never diagonal), b = kt+4 ----
  for (; kt + 4 < ntile; kt += 8) {
    const unsigned short* ka = kbase + (size_t)kt * 2048;
    const unsigned short* va = vbase + (size_t)kt * 2048;
    bf16x8 kfa[4], kfb[4], vaa[4], vab[4];
#pragma unroll
    for (int j = 0; j < 4; ++j) {
      kfa[j] = *(const bf16x8*)(ka + 512 * j + l * 8);
      kfb[j] = *(const bf16x8*)(ka + 4 * 2048 + 512 * j + l * 8);
      vaa[j] = *(const bf16x8*)(va + 512 * j + l * 8);
      vab[j] = *(const bf16x8*)(va + 4 * 2048 + 512 * j + l * 8);
    }
    f32x16 sa = (f32x16)0.f, sb = (f32x16)0.f;
    __builtin_amdgcn_s_setprio(1);
#pragma unroll
    for (int j = 0; j < 4; ++j) sa = mfma32(kfa[j], qf[j], sa);
#pragma unroll
    for (int j = 0; j < 4; ++j) sb = mfma32(kfb[j], qf[j], sb);
    __builtin_amdgcn_s_setprio(0);

    float p[32];
#pragma unroll
    for (int r = 0; r < 16; ++r) p[r] = sa[r];
    if (kt + 4 == ntile - 1) {  // tile b is the diagonal tile
#pragma unroll
      for (int r = 0; r < 16; ++r) {
        int key = (kt + 4) * 32 + (r & 3) + 8 * (r >> 2) + 4 * hi;
        p[16 + r] = (key > qg) ? -1e30f : sb[r];
      }
    } else {
#pragma unroll
      for (int r = 0; r < 16; ++r) p[16 + r] = sb[r];
    }
    // single merged max over 64 keys (T17 triples)
    float a0 = fmaxf(fmaxf(p[0], p[1]), p[2]);
    float a1 = fmaxf(fmaxf(p[3], p[4]), p[5]);
    float a2 = fmaxf(fmaxf(p[6], p[7]), p[8]);
    float a3 = fmaxf(fmaxf(p[9], p[10]), p[11]);
    float a4 = fmaxf(fmaxf(p[12], p[13]), p[14]);
    float b0 = fmaxf(fmaxf(p[15], p[16]), p[17]);
    float b1 = fmaxf(fmaxf(p[18], p[19]), p[20]);
    float b2 = fmaxf(fmaxf(p[21], p[22]), p[23]);
    float b3 = fmaxf(fmaxf(p[24], p[25]), p[26]);
    float b4 = fmaxf(fmaxf(p[27], p[28]), p[29]);
    float b5 = fmaxf(p[30], p[31]);
    float mt = fmaxf(fmaxf(fmaxf(fmaxf(a0, a1), fmaxf(a2, a3)),
                           fmaxf(fmaxf(a4, b0), fmaxf(b1, b2))),
                     fmaxf(fmaxf(b3, b4), b5));
    float mto = mt;
    plswapf(mt, mto);
    mt = fmaxf(mt, mto);
    if (!__all(mt - mrun <= 8.f)) {
      float mnew = fmaxf(mrun, mt);
      float al = __builtin_amdgcn_exp2f(mrun - mnew);
      mrun = mnew;
      lrun *= al;
      o0 *= al;
      o1 *= al;
    }
#pragma unroll
    for (int r = 0; r < 32; ++r) p[r] = __builtin_amdgcn_exp2f(p[r] - mrun);
    float s0 = (p[0] + p[1]) + (p[2] + p[3]);
    float s1 = (p[4] + p[5]) + (p[6] + p[7]);
    float s2 = (p[8] + p[9]) + (p[10] + p[11]);
    float s3 = (p[12] + p[13]) + (p[14] + p[15]);
    float s4 = (p[16] + p[17]) + (p[18] + p[19]);
    float s5 = (p[20] + p[21]) + (p[22] + p[23]);
    float s6 = (p[24] + p[25]) + (p[26] + p[27]);
    float s7 = (p[28] + p[29]) + (p[30] + p[31]);
    float ts = ((s0 + s1) + (s2 + s3)) + ((s4 + s5) + (s6 + s7));
    float tso = ts;
    plswapf(ts, tso);
    ts += tso;
    lrun += ts;
    // P -> bf16 B-fragments via cvt_pk + permlane32_swap (T12), both tiles.
    union B8 { unsigned u[4]; bf16x8 v; } pb0a, pb1a, pb0b, pb1b;
    {
      unsigned t0 = cvtpk(p[0], p[1]), t1 = cvtpk(p[4], p[5]);
      plswap(t0, t1);
      pb0a.u[0] = t0; pb0a.u[2] = t1;
    }
    {
      unsigned t0 = cvtpk(p[2], p[3]), t1 = cvtpk(p[6], p[7]);
      plswap(t0, t1);
      pb0a.u[1] = t0; pb0a.u[3] = t1;
    }
    {
      unsigned t0 = cvtpk(p[8], p[9]), t1 = cvtpk(p[12], p[13]);
      plswap(t0, t1);
      pb1a.u[0] = t0; pb1a.u[2] = t1;
    }
    {
      unsigned t0 = cvtpk(p[10], p[11]), t1 = cvtpk(p[14], p[15]);
      plswap(t0, t1);
      pb1a.u[1] = t0; pb1a.u[3] = t1;
    }
    {
      unsigned t0 = cvtpk(p[16], p[17]), t1 = cvtpk(p[20], p[21]);
      plswap(t0, t1);
      pb0b.u[0] = t0; pb0b.u[2] = t1;
    }
    {
      unsigned t0 = cvtpk(p[18], p[19]), t1 = cvtpk(p[22], p[23]);
      plswap(t0, t1);
      pb0b.u[1] = t0; pb0b.u[3] = t1;
    }
    {
      unsigned t0 = cvtpk(p[24], p[25]), t1 = cvtpk(p[28], p[29]);
      plswap(t0, t1);
      pb1b.u[0] = t0; pb1b.u[2] = t1;
    }
    {
      unsigned t0 = cvtpk(p[26], p[27]), t1 = cvtpk(p[30], p[31]);
      plswap(t0, t1);
      pb1b.u[1] = t0; pb1b.u[3] = t1;
    }
    __builtin_amdgcn_s_setprio(1);
    o0 = mfma32(vaa[0], pb0a.v, o0);
    o0 = mfma32(vaa[1], pb1a.v, o0);
    o1 = mfma32(vaa[2], pb0a.v, o1);
    o1 = mfma32(vaa[3], pb1a.v, o1);
    o0 = mfma32(vab[0], pb0b.v, o0);
    o0 = mfma32(vab[1], pb1b.v, o0);
    o1 = mfma32(vab[2], pb0b.v, o1);
    o1 = mfma32(vab[3], pb1b.v, o1);
    __builtin_amdgcn_s_setprio(0);
  }
  // ---- tail: at most one remaining tile ----
  if (kt < ntile) {
    const int key0 = kt << 5;
    const unsigned short* kvt = kbase + (size_t)kt * 2048;
    bf16x8 kf0 = *(const bf16x8*)(kvt + l * 8);
    bf16x8 kf1 = *(const bf16x8*)(kvt + 512 + l * 8);
    bf16x8 kf2 = *(const bf16x8*)(kvt + 1024 + l * 8);
    bf16x8 kf3 = *(const bf16x8*)(kvt + 1536 + l * 8);
    const unsigned short* vvt = vbase + (size_t)kt * 2048;
    bf16x8 va00 = *(const bf16x8*)(vvt + l * 8);
    bf16x8 va01 = *(const bf16x8*)(vvt + 512 + l * 8);
    bf16x8 va10 = *(const bf16x8*)(vvt + 1024 + l * 8);
    bf16x8 va11 = *(const bf16x8*)(vvt + 1536 + l * 8);

    f32x16 s = (f32x16)0.f;
    __builtin_amdgcn_s_setprio(1);
    s = mfma32(kf0, qf[0], s);
    s = mfma32(kf1, qf[1], s);
    s = mfma32(kf2, qf[2], s);
    s = mfma32(kf3, qf[3], s);
    __builtin_amdgcn_s_setprio(0);

    float p[16];
    if (kt == ntile - 1) {  // diagonal tile: causal mask
#pragma unroll
      for (int r = 0; r < 16; ++r) {
        int key = key0 + (r & 3) + 8 * (r >> 2) + 4 * hi;
        p[r] = (key > qg) ? -1e30f : s[r];
      }
    } else {
#pragma unroll
      for (int r = 0; r < 16; ++r) p[r] = s[r];
    }
    float a0 = fmaxf(fmaxf(p[0], p[1]), p[2]);
    float a1 = fmaxf(fmaxf(p[3], p[4]), p[5]);
    float a2 = fmaxf(fmaxf(p[6], p[7]), p[8]);
    float a3 = fmaxf(fmaxf(p[9], p[10]), p[11]);
    float a4 = fmaxf(fmaxf(p[12], p[13]), p[14]);
    float mt = fmaxf(fmaxf(fmaxf(a0, a1), a2), fmaxf(fmaxf(a3, a4), p[15]));
    float mto = mt;
    plswapf(mt, mto);
    mt = fmaxf(mt, mto);
    if (!__all(mt - mrun <= 8.f)) {
      float mnew = fmaxf(mrun, mt);
      float al = __builtin_amdgcn_exp2f(mrun - mnew);
      mrun = mnew;
      lrun *= al;
      o0 *= al;
      o1 *= al;
    }
#pragma unroll
    for (int r = 0; r < 16; ++r) p[r] = __builtin_amdgcn_exp2f(p[r] - mrun);
    float s0 = (p[0] + p[1]) + (p[2] + p[3]);
    float s1 = (p[4] + p[5]) + (p[6] + p[7]);
    float s2 = (p[8] + p[9]) + (p[10] + p[11]);
    float s3 = (p[12] + p[13]) + (p[14] + p[15]);
    float ts = (s0 + s1) + (s2 + s3);
    float tso = ts;
    plswapf(ts, tso);
    ts += tso;
    lrun += ts;
    union B8 { unsigned u[4]; bf16x8 v; } pb0, pb1;
    {
      unsigned t0 = cvtpk(p[0], p[1]), t1 = cvtpk(p[4], p[5]);
      plswap(t0, t1);
      pb0.u[0] = t0; pb0.u[2] = t1;
    }
    {
      unsigned t0 = cvtpk(p[2], p[3]), t1 = cvtpk(p[6], p[7]);
      plswap(t0, t1);
      pb0.u[1] = t0; pb0.u[3] = t1;
    }
    {
      unsigned t0 = cvtpk(p[8], p[9]), t1 = cvtpk(p[12], p[13]);
      plswap(t0, t1);
      pb1.u[0] = t0; pb1.u[2] = t1;
    }
    {
      unsigned t0 = cvtpk(p[10], p[11]), t1 = cvtpk(p[14], p[15]);
      plswap(t0, t1);
      pb1.u[1] = t0; pb1.u[3] = t1;
    }
    __builtin_amdgcn_s_setprio(1);
    o0 = mfma32(va00, pb0.v, o0);
    o0 = mfma32(va01, pb1.v, o0);
    o1 = mfma32(va10, pb0.v, o1);
    o1 = mfma32(va11, pb1.v, o1);
    __builtin_amdgcn_s_setprio(0);
  }

  // ---- two-phase split-K combine (o0 then o1, 19.4 KB LDS) ----
  // o-reg r of o{dh} maps to d = (r&3) + 8*(r>>2) + 4*hi + 32*dh;
  // wave wv combines regs [wv*4, wv*4+4) of each phase.
  {
    union F16 { f32x16 v; f32x4 q[4]; } uu;
    uu.v = o0;
    float* dst = &buf[wv][l][0];
#pragma unroll
    for (int i = 0; i < 4; ++i) *(f32x4*)(dst + 4 * i) = uu.q[i];
    dst[16] = mrun;
    dst[17] = lrun;
  }
  __syncthreads();
  float mfin = -1e30f;
#pragma unroll
  for (int w2 = 0; w2 < 4; ++w2) mfin = fmaxf(mfin, buf[w2][l][16]);
  float lsum = 0.f;
  float scl[4];
#pragma unroll
  for (int w2 = 0; w2 < 4; ++w2) {
    scl[w2] = __builtin_amdgcn_exp2f(buf[w2][l][16] - mfin);
    lsum += buf[w2][l][17] * scl[w2];
  }
  const float inv = 1.f / lsum;
  unsigned short* obase = aob + (size_t)qg * DMODEL + h * 64;
  {
    f32x4 acc = (f32x4)0.f;
#pragma unroll
    for (int w2 = 0; w2 < 4; ++w2)
      acc += *(const f32x4*)&buf[w2][l][wv * 4] * scl[w2];
    unsigned u0 = cvtpk(acc[0] * inv, acc[1] * inv);
    unsigned u1 = cvtpk(acc[2] * inv, acc[3] * inv);
    unsigned short* dsto = obase + 8 * wv + 4 * hi;
    *(unsigned*)(dsto) = u0;
    *(unsigned*)(dsto + 2) = u1;
  }
  __syncthreads();  // all phase-A reads done before overwrite
  {
    union F16 { f32x16 v; f32x4 q[4]; } uu;
    uu.v = o1;
    float* dst = &buf[wv][l][0];
#pragma unroll
    for (int i = 0; i < 4; ++i) *(f32x4*)(dst + 4 * i) = uu.q[i];
  }
  __syncthreads();
  {
    f32x4 acc = (f32x4)0.f;
#pragma unroll
    for (int w2 = 0; w2 < 4; ++w2)
      acc += *(const f32x4*)&buf[w2][l][wv * 4] * scl[w2];
    unsigned u0 = cvtpk(acc[0] * inv, acc[1] * inv);
    unsigned u1 = cvtpk(acc[2] * inv, acc[3] * inv);
    unsigned short* dsto = obase + 32 + 8 * wv + 4 * hi;
    *(unsigned*)(dsto) = u0;
    *(unsigned*)(dsto + 2) = u1;
  }
}

extern "C" void kernel_launch(void* const* d_in, const int* in_sizes, int n_in,
                              void* d_out, int out_size, void* d_ws,
                              size_t ws_size, hipStream_t stream) {
  const float* x = (const float*)d_in[0];
  const float* cosb = (const float*)d_in[1];
  const float* sinb = (const float*)d_in[2];
  const float* wqkv = (const float*)d_in[3];
  const float* wo = (const float*)d_in[4];
  float* out = (float*)d_out;
  char* ws = (char*)d_ws;
  float* qkv = (float*)(ws);                               // 25,165,824
  unsigned short* xb = (unsigned short*)(ws + 25165824);   //  8,388,608
  unsigned short* wb = (unsigned short*)(ws + 33554432);   // 12,582,912
  unsigned short* wob = (unsigned short*)(ws + 46137344);  //  8,388,608
  unsigned short* qb = (unsigned short*)(ws + 54525952);   //  8,388,608
  unsigned short* kft = (unsigned short*)(ws + 62914560);  //  2,097,152
  unsigned short* vft = (unsigned short*)(ws + 65011712);  //  2,097,152
  unsigned short* aob = (unsigned short*)(ws + 67108864);  //  8,388,608

  cast3_kernel<<<dim3(3670016 / 256), 256, 0, stream>>>(x, wqkv, wo, xb, wb,
                                                        wob);
  gemm_bt<<<dim3(48, 16), 256, 0, stream>>>(xb, wb, qkv, 2048, 3072, 2048);
  rope_split<<<dim3(2048), 256, 0, stream>>>(qkv, cosb, sinb, qb, kft);
  v_transpose<<<dim3(8, 32), 256, 0, stream>>>(qkv, vft);
  attn_kernel<<<dim3(2048), 256, 0, stream>>>(qb, kft, vft, aob);
  gemm_bt<<<dim3(32, 16), 256, 0, stream>>>(aob, wob, out, 2048, 2048, 2048);
}